// Round 9
// baseline (233.511 us; speedup 1.0000x reference)
//
#include <hip/hip_runtime.h>
#include <hip/hip_bf16.h>

// TransformerMultiheadAttention: B=2, L=2048, D=1024, H=16, HD=64, causal.
// f32 in/out; bf16 MFMA internally. 4 dispatches:
//   xcvt:     Q,K,V,wq,wk,wv,wo f32 -> bf16, 4 float4/thread, grid (1024,4)
//   gemm_qkv: pure-bf16 128x128 GEMM, BK=64 (16 k-steps, 32 MFMA/round),
//             XOR-granule-swizzled LDS; qp pre-scaled 0.125*log2(e);
//             vt stored transposed [B,H,HD,L] via LDS-transpose epilogue.
//             XCD-chunked block swizzle (768 = 8*96). grid (32,8,3).
//   attn:     UNPAIRED causal flash attn: 1 band/block, grid (16,32,2)=1024
//             blocks (longest band first), 3 blocks/CU. Swapped QK^T (S^T)
//             -> packed b64 P stores (stride-72 rows), scalar per-lane row
//             sums via exp2 (log2e pre-folded), setprio around MFMA clusters.
//             K/V LDS dbuf staging, 1 barrier/tile.
//   gemm_out: out = at @ wo^T + bo (f32), 128x128 BK=64 tiles, 256 blocks
//             (exactly 1/CU), XCD swizzle (256 = 8*32).

#define B_ 2
#define L_ 2048
#define D_ 1024
#define H_ 16
#define HD_ 64
#define NA_ ((size_t)B_ * L_ * D_)   // 4M elems
#define NW_ ((size_t)D_ * D_)        // 1M elems

typedef __attribute__((ext_vector_type(8))) short bf16x8;   // 8 bf16 = 4 VGPR
typedef __attribute__((ext_vector_type(4))) float f32x4;
typedef __hip_bfloat16 bf16;

__device__ __forceinline__ void async_load16(const void* g, void* l) {
  __builtin_amdgcn_global_load_lds((const __attribute__((address_space(1))) void*)g,
                                   (__attribute__((address_space(3))) void*)l,
                                   16, 0, 0);
}

// Convert Q,K,V + 4 weights f32 -> bf16 into one packed buffer.
// dst layout: [Qb NA][Kb NA][Vb NA][w0 NW][w1 NW][w2 NW][w3 NW].
// grid (NA/4096, 4): y<3 = Q/K/V; y==3 = all four weights packed (4*NW == NA).
__global__ __launch_bounds__(256) void xcvt_kernel(const float* __restrict__ q,
                                                   const float* __restrict__ k,
                                                   const float* __restrict__ v,
                                                   const float* __restrict__ w0,
                                                   const float* __restrict__ w1,
                                                   const float* __restrict__ w2,
                                                   const float* __restrict__ w3,
                                                   bf16* __restrict__ dst) {
  const int y = blockIdx.y;
  const size_t base = (size_t)blockIdx.x * 4096 + (size_t)threadIdx.x * 4;
#pragma unroll
  for (int j = 0; j < 4; j++) {
    size_t i = base + (size_t)j * 1024;
    const float* src;
    size_t soff = i;
    if (y < 3) {
      src = (y == 0) ? q : (y == 1) ? k : v;
    } else {
      int w = (int)(i >> 20);  // NW_ = 2^20 elems per weight; uniform per block
      src = (w == 0) ? w0 : (w == 1) ? w1 : (w == 2) ? w2 : w3;
      soff = i & (NW_ - 1);
    }
    float4 vv = *(const float4*)(src + soff);
    union { bf16 h[4]; uint2 u; } pk;
    pk.h[0] = __float2bfloat16(vv.x);
    pk.h[1] = __float2bfloat16(vv.y);
    pk.h[2] = __float2bfloat16(vv.z);
    pk.h[3] = __float2bfloat16(vv.w);
    *(uint2*)(dst + (size_t)y * NA_ + i) = pk.u;
  }
}

// Fused Q/K/V projection, 128x128 tiles, BK=64 (16 k-steps, 32 MFMA/round).
// LDS XOR-granule swizzle: staged via pre-swizzled global column, frag reads
// deswizzle with (l16&7) -> 2-way banked b128 reads. grid (32,8,3), XCD swz.
// z==2 (V) epilogue: LDS transpose -> coalesced 16B stores into vt [B,H,HD,L].
#define TS_ 136  // transpose-tile elem stride (272B rows, 16B aligned)
__global__ __launch_bounds__(256) void gemm_qkv(const bf16* __restrict__ Qb,
                                                const bf16* __restrict__ Kb,
                                                const bf16* __restrict__ Vb,
                                                const bf16* __restrict__ Wb,
                                                bf16* __restrict__ qp,
                                                bf16* __restrict__ kp,
                                                bf16* __restrict__ vtp) {
  __shared__ __align__(16) bf16 smem[128 * TS_];  // As(16K)+Bs(16K) | T(34K B)
  bf16* As = smem;                 // [128][64] swizzled granules
  bf16* Bs = smem + 128 * 64;
  const int tid = threadIdx.x;
  const int wv = tid >> 6, lane = tid & 63;
  const int quad = lane >> 4, l16 = lane & 15;
  const int wm = wv & 1, wn = wv >> 1;
  // XCD-chunked swizzle: 768 blocks = 8 XCDs x 96.
  const int id = blockIdx.x + 32 * blockIdx.y + 256 * blockIdx.z;
  const int swz = (id & 7) * 96 + (id >> 3);
  const int m0 = (swz & 31) * 128, n0 = ((swz >> 5) & 7) * 128;
  const int z = swz >> 8;
  const bf16* X = (z == 0) ? Qb : (z == 1) ? Kb : Vb;
  const bf16* W = Wb + (size_t)z * NW_;

  f32x4 acc[4][4];
#pragma unroll
  for (int i = 0; i < 4; i++)
#pragma unroll
    for (int j = 0; j < 4; j++) acc[i][j] = (f32x4){0.f, 0.f, 0.f, 0.f};

  for (int k0 = 0; k0 < D_; k0 += 64) {
#pragma unroll
    for (int it = 0; it < 4; it++) {
      int c = (wv * 4 + it) * 64 + lane;      // slot 0..1023
      int row = c >> 3, cc = (c & 7) ^ (row & 7);  // pre-swizzled src granule
      async_load16(X + (size_t)(m0 + row) * D_ + k0 + cc * 8, (char*)As + c * 16);
      async_load16(W + (size_t)(n0 + row) * D_ + k0 + cc * 8, (char*)Bs + c * 16);
    }
    __syncthreads();
#pragma unroll
    for (int kq = 0; kq < 2; kq++) {
      const int g = (((kq * 4 + quad) ^ (l16 & 7)) * 8);
      bf16x8 af[4], bfr[4];
#pragma unroll
      for (int mi = 0; mi < 4; mi++)
        af[mi] = *(const bf16x8*)&As[(wm * 64 + mi * 16 + l16) * 64 + g];
#pragma unroll
      for (int ni = 0; ni < 4; ni++)
        bfr[ni] = *(const bf16x8*)&Bs[(wn * 64 + ni * 16 + l16) * 64 + g];
#pragma unroll
      for (int mi = 0; mi < 4; mi++)
#pragma unroll
        for (int ni = 0; ni < 4; ni++)
          acc[mi][ni] = __builtin_amdgcn_mfma_f32_16x16x32_bf16(af[mi], bfr[ni],
                                                                acc[mi][ni], 0, 0, 0);
    }
    __syncthreads();
  }

  if (z == 2) {
    // Transpose epilogue: T[n_loc][m_loc], 4 m-consecutive accs -> ds_write_b64.
    bf16* T = smem;
#pragma unroll
    for (int mi = 0; mi < 4; mi++) {
#pragma unroll
      for (int ni = 0; ni < 4; ni++) {
        int n_loc = wn * 64 + ni * 16 + l16;
        int m_loc = wm * 64 + mi * 16 + quad * 4;
        union { bf16 hx[4]; uint2 d; } pk;
#pragma unroll
        for (int r = 0; r < 4; r++) pk.hx[r] = __float2bfloat16(acc[mi][ni][r]);
        *(uint2*)&T[n_loc * TS_ + m_loc] = pk.d;
      }
    }
    __syncthreads();
    // 8 passes: 16 threads per n-row read b128 (m-contig) -> 256B coalesced store.
#pragma unroll
    for (int p = 0; p < 8; p++) {
      int n_loc = p * 16 + (tid >> 4);
      int m_loc = (tid & 15) * 8;
      bf16x8 vv = *(const bf16x8*)&T[n_loc * TS_ + m_loc];
      int n = n0 + n_loc;
      int m = m0 + m_loc;
      int bb = m >> 11, l = m & (L_ - 1);
      int hh = n >> 6, hd = n & 63;
      *(bf16x8*)&vtp[((size_t)((bb * H_ + hh) * HD_ + hd)) * L_ + l] = vv;
    }
  } else {
    // qp pre-scaled by 0.125 * log2(e) so attn can use raw v_exp_f32 (2^x).
    const float sc = (z == 0) ? 0.18033688f : 1.0f;
    bf16* dst = (z == 0) ? qp : kp;
#pragma unroll
    for (int mi = 0; mi < 4; mi++) {
#pragma unroll
      for (int ni = 0; ni < 4; ni++) {
        int n = n0 + wn * 64 + ni * 16 + l16;
#pragma unroll
        for (int r = 0; r < 4; r++) {
          int m = m0 + wm * 64 + mi * 16 + quad * 4 + r;
          dst[(size_t)m * D_ + n] = __float2bfloat16(acc[mi][ni][r] * sc);
        }
      }
    }
  }
}

// Unpaired causal flash attention. grid (H, 32, B) = 1024 blocks,
// band = 31 - blockIdx.y (longest bands dispatch first). 3 blocks/CU.
// S^T = mfma(K,Q): lane(l16) owns q-row, 4 consecutive keys per (ss,quad).
// exp2-based softmax (log2e folded into qp), rcp-based normalize.
__global__ __launch_bounds__(256) void attn_kernel(const bf16* __restrict__ qp,
                                                   const bf16* __restrict__ kp,
                                                   const bf16* __restrict__ vt,
                                                   bf16* __restrict__ attn) {
  __shared__ __align__(16) bf16 Kt[2][64 * 64];  // swizzled [key][hd]
  __shared__ __align__(16) bf16 Vt[2][64 * 64];  // swizzled [hd][key]
  __shared__ __align__(16) bf16 P[4][16 * 72];   // per-wave [q][key]
  const int tid = threadIdx.x;
  const int wv = tid >> 6, lane = tid & 63;
  const int quad = lane >> 4, l16 = lane & 15;
  const int h = blockIdx.x, band = 31 - (int)blockIdx.y, b = blockIdx.z;

  const int rq = band * 64 + wv * 16 + l16;  // this lane's q-row (S^T col)
  bf16x8 qa[2];
#pragma unroll
  for (int kk = 0; kk < 2; kk++)
    qa[kk] = *(const bf16x8*)&qp[((size_t)(b * L_ + rq)) * D_ + h * HD_ +
                                 kk * 32 + quad * 8];

  f32x4 O[4];
#pragma unroll
  for (int t = 0; t < 4; t++) O[t] = (f32x4){0.f, 0.f, 0.f, 0.f};
  float l = 0.f;  // per-lane row sum for q = rq

  const int csw = quad ^ (l16 & 7);  // swizzled base chunk for frag reads

  auto stage = [&](int j, int buf) {
    const int j0 = j * 64;
#pragma unroll
    for (int it = 0; it < 2; it++) {
      int slot = (wv * 2 + it) * 64 + lane;
      int row = slot >> 3, c = (slot & 7) ^ (row & 7);
      async_load16(kp + ((size_t)(b * L_ + j0 + row)) * D_ + h * HD_ + c * 8,
                   (char*)Kt[buf] + slot * 16);
      async_load16(vt + ((size_t)((b * H_ + h) * HD_ + row)) * L_ + j0 + c * 8,
                   (char*)Vt[buf] + slot * 16);
    }
  };

  stage(0, 0);
  for (int j = 0; j <= band; j++) {
    const int buf = j & 1;
    const int j0 = j * 64;
    __syncthreads();
    if (j < band) stage(j + 1, buf ^ 1);

    // S^T = K Q^T (0.125*log2e pre-folded): s[ss][r] = S[key][q=l16-row]
    f32x4 s[4];
    __builtin_amdgcn_s_setprio(1);
#pragma unroll
    for (int ss = 0; ss < 4; ss++) {
      int krow = ss * 16 + l16;
      bf16x8 kb0 = *(const bf16x8*)&Kt[buf][krow * 64 + csw * 8];
      bf16x8 kb1 = *(const bf16x8*)&Kt[buf][krow * 64 + (csw ^ 4) * 8];
      f32x4 t = (f32x4){0.f, 0.f, 0.f, 0.f};
      t = __builtin_amdgcn_mfma_f32_16x16x32_bf16(kb0, qa[0], t, 0, 0, 0);
      t = __builtin_amdgcn_mfma_f32_16x16x32_bf16(kb1, qa[1], t, 0, 0, 0);
      s[ss] = t;
    }
    __builtin_amdgcn_s_setprio(0);

    if (j == band) {  // diagonal tile: causal mask
#pragma unroll
      for (int ss = 0; ss < 4; ss++)
#pragma unroll
        for (int r = 0; r < 4; r++) {
          int key = j0 + ss * 16 + quad * 4 + r;
          if (key > rq) s[ss][r] = -1e30f;
        }
    }

    // exp2 + pack 4 consecutive keys -> one ds_write_b64 per ss (wave-private).
#pragma unroll
    for (int ss = 0; ss < 4; ss++) {
      float p0 = exp2f(s[ss][0]), p1 = exp2f(s[ss][1]);
      float p2 = exp2f(s[ss][2]), p3 = exp2f(s[ss][3]);
      l += (p0 + p1) + (p2 + p3);
      union { bf16 hx[4]; uint2 d; } pk;
      pk.hx[0] = __float2bfloat16(p0);
      pk.hx[1] = __float2bfloat16(p1);
      pk.hx[2] = __float2bfloat16(p2);
      pk.hx[3] = __float2bfloat16(p3);
      *(uint2*)&P[wv][l16 * 72 + ss * 16 + quad * 4] = pk.d;
    }

    // P region is per-wave: order writes->reads without draining vmcnt.
    asm volatile("s_waitcnt lgkmcnt(0)" ::: "memory");

    // O += P V
    __builtin_amdgcn_s_setprio(1);
#pragma unroll
    for (int kk = 0; kk < 2; kk++) {
      bf16x8 pa = *(const bf16x8*)&P[wv][l16 * 72 + kk * 32 + quad * 8];
#pragma unroll
      for (int t = 0; t < 4; t++) {
        bf16x8 vb = *(const bf16x8*)&Vt[buf][(t * 16 + l16) * 64 + (csw ^ (kk * 4)) * 8];
        O[t] = __builtin_amdgcn_mfma_f32_16x16x32_bf16(pa, vb, O[t], 0, 0, 0);
      }
    }
    __builtin_amdgcn_s_setprio(0);
  }

  // Row sums: quad-reduce (2 shuffles), redistribute to fragment rows,
  // then approximate-reciprocal normalize (bf16 output: 1ulp rcp is plenty).
  l += __shfl_xor(l, 16, 64);
  l += __shfl_xor(l, 32, 64);
  float rl[4];
#pragma unroll
  for (int r = 0; r < 4; r++)
    rl[r] = __builtin_amdgcn_rcpf(__shfl(l, quad * 4 + r, 64));

#pragma unroll
  for (int t = 0; t < 4; t++) {
#pragma unroll
    for (int r = 0; r < 4; r++) {
      int row = band * 64 + wv * 16 + quad * 4 + r;
      attn[((size_t)(b * L_ + row)) * D_ + h * HD_ + t * 16 + l16] =
          __float2bfloat16(O[t][r] * rl[r]);
    }
  }
}

// out = at @ wo^T + bo, f32 store. 128x128 BK=64 tiles -> grid (32, 8) = 256
// blocks = exactly 1/CU (tail-free), XCD-chunked swizzle (256 = 8*32).
__global__ __launch_bounds__(256) void gemm_out(const bf16* __restrict__ X,
                                                const bf16* __restrict__ W,
                                                const float* __restrict__ bias,
                                                float* __restrict__ out) {
  __shared__ __align__(16) bf16 As[128 * 64];
  __shared__ __align__(16) bf16 Bs[128 * 64];
  const int tid = threadIdx.x;
  const int wv = tid >> 6, lane = tid & 63;
  const int quad = lane >> 4, l16 = lane & 15;
  const int wm = wv & 1, wn = wv >> 1;
  const int id = blockIdx.x + 32 * blockIdx.y;
  const int swz = (id & 7) * 32 + (id >> 3);
  const int m0 = (swz & 31) * 128, n0 = (swz >> 5) * 128;

  f32x4 acc[4][4];
#pragma unroll
  for (int i = 0; i < 4; i++)
#pragma unroll
    for (int j = 0; j < 4; j++) acc[i][j] = (f32x4){0.f, 0.f, 0.f, 0.f};

  for (int k0 = 0; k0 < D_; k0 += 64) {
#pragma unroll
    for (int it = 0; it < 4; it++) {
      int c = (wv * 4 + it) * 64 + lane;
      int row = c >> 3, cc = (c & 7) ^ (row & 7);
      async_load16(X + (size_t)(m0 + row) * D_ + k0 + cc * 8, (char*)As + c * 16);
      async_load16(W + (size_t)(n0 + row) * D_ + k0 + cc * 8, (char*)Bs + c * 16);
    }
    __syncthreads();
#pragma unroll
    for (int kq = 0; kq < 2; kq++) {
      const int g = (((kq * 4 + quad) ^ (l16 & 7)) * 8);
      bf16x8 af[4], bfr[4];
#pragma unroll
      for (int mi = 0; mi < 4; mi++)
        af[mi] = *(const bf16x8*)&As[(wm * 64 + mi * 16 + l16) * 64 + g];
#pragma unroll
      for (int ni = 0; ni < 4; ni++)
        bfr[ni] = *(const bf16x8*)&Bs[(wn * 64 + ni * 16 + l16) * 64 + g];
#pragma unroll
      for (int mi = 0; mi < 4; mi++)
#pragma unroll
        for (int ni = 0; ni < 4; ni++)
          acc[mi][ni] = __builtin_amdgcn_mfma_f32_16x16x32_bf16(af[mi], bfr[ni],
                                                                acc[mi][ni], 0, 0, 0);
    }
    __syncthreads();
  }

#pragma unroll
  for (int mi = 0; mi < 4; mi++) {
#pragma unroll
    for (int ni = 0; ni < 4; ni++) {
      int n = n0 + wn * 64 + ni * 16 + l16;
      float bval = bias[n];
#pragma unroll
      for (int r = 0; r < 4; r++) {
        int m = m0 + wm * 64 + mi * 16 + quad * 4 + r;
        out[(size_t)m * D_ + n] = acc[mi][ni][r] + bval;
      }
    }
  }
}

extern "C" void kernel_launch(void* const* d_in, const int* in_sizes, int n_in,
                              void* d_out, int out_size, void* d_ws, size_t ws_size,
                              hipStream_t stream) {
  const float* Q  = (const float*)d_in[0];
  const float* K  = (const float*)d_in[1];
  const float* V  = (const float*)d_in[2];
  // d_in[3]: causal mask (int32) -- deterministic tril, not read
  const float* wq = (const float*)d_in[4];
  const float* wk = (const float*)d_in[5];
  const float* wvp = (const float*)d_in[6];
  const float* wo = (const float*)d_in[7];
  const float* bo = (const float*)d_in[8];
  float* out = (float*)d_out;

  bf16* base = (bf16*)d_ws;           // packed: Qb,Kb,Vb, W[4], qp,kp,vt,at
  bf16* Qb = base;
  bf16* Kb = Qb + NA_;
  bf16* Vb = Kb + NA_;
  bf16* Wb = Vb + NA_;                // 4 weights
  bf16* qp = Wb + 4 * NW_;
  bf16* kp = qp + NA_;
  bf16* vt = kp + NA_;
  bf16* at = vt + NA_;                // total 64 MB

  xcvt_kernel<<<dim3(NA_ / 4096, 4), 256, 0, stream>>>(Q, K, V, wq, wk, wvp, wo, base);
  gemm_qkv<<<dim3(32, 8, 3), 256, 0, stream>>>(Qb, Kb, Vb, Wb, qp, kp, vt);
  attn_kernel<<<dim3(H_, L_ / 64, B_), 256, 0, stream>>>(qp, kp, vt, at);
  gemm_out<<<dim3(32, 8), 256, 0, stream>>>(at, Wb + 3 * NW_, bo, out);
}

// Round 10
// 215.692 us; speedup vs baseline: 1.0826x; 1.0826x over previous
//
#include <hip/hip_runtime.h>
#include <hip/hip_bf16.h>

// TransformerMultiheadAttention: B=2, L=2048, D=1024, H=16, HD=64, causal.
// f32 in/out; bf16 MFMA internally. 4 dispatches:
//   xcvt:     Q,K,V,wq,wk,wv,wo f32 -> bf16, 4 float4/thread, grid (1024,4)
//   gemm_qkv: pure-bf16 m97-pattern 128x128 GEMM (BK=32); qp pre-scaled
//             0.125*log2(e) for exp2 softmax; vt stored transposed [B,H,HD,L]
//             via LDS-transpose epilogue. XCD swizzle (768=8*96). grid (32,8,3).
//   attn:     UNPAIRED causal flash attn: 1 band/block, grid (16,32,2)=1024
//             blocks (longest band first), 3 blocks/CU. Swapped QK^T (S^T)
//             -> packed b64 P stores (stride-72 rows), scalar per-lane row
//             sums via raw v_exp_f32 (log2e pre-folded), rcp normalize,
//             setprio around MFMA clusters. K/V LDS dbuf, 1 barrier/tile.
//   gemm_out: out = at @ wo^T + bo (f32), 128x128 m97 tiles (BK=32), 256
//             blocks (exactly 1/CU), XCD swizzle (256 = 8*32).

#define B_ 2
#define L_ 2048
#define D_ 1024
#define H_ 16
#define HD_ 64
#define NA_ ((size_t)B_ * L_ * D_)   // 4M elems
#define NW_ ((size_t)D_ * D_)        // 1M elems

typedef __attribute__((ext_vector_type(8))) short bf16x8;   // 8 bf16 = 4 VGPR
typedef __attribute__((ext_vector_type(4))) float f32x4;
typedef __hip_bfloat16 bf16;

__device__ __forceinline__ void async_load16(const void* g, void* l) {
  __builtin_amdgcn_global_load_lds((const __attribute__((address_space(1))) void*)g,
                                   (__attribute__((address_space(3))) void*)l,
                                   16, 0, 0);
}

// Raw 2^x (single v_exp_f32). Fallback multiplies by ln2 (still correct: the
// qp scale pre-folds log2e, so exp(ln2*x) == 2^x == exp of the raw score).
__device__ __forceinline__ float fast_exp2(float x) {
#if __has_builtin(__builtin_amdgcn_exp2f)
  return __builtin_amdgcn_exp2f(x);
#else
  return __expf(0.69314718f * x);
#endif
}

// Convert Q,K,V + 4 weights f32 -> bf16 into one packed buffer.
// dst layout: [Qb NA][Kb NA][Vb NA][w0 NW][w1 NW][w2 NW][w3 NW].
// grid (NA/4096, 4): y<3 = Q/K/V; y==3 = all four weights packed (4*NW == NA).
__global__ __launch_bounds__(256) void xcvt_kernel(const float* __restrict__ q,
                                                   const float* __restrict__ k,
                                                   const float* __restrict__ v,
                                                   const float* __restrict__ w0,
                                                   const float* __restrict__ w1,
                                                   const float* __restrict__ w2,
                                                   const float* __restrict__ w3,
                                                   bf16* __restrict__ dst) {
  const int y = blockIdx.y;
  const size_t base = (size_t)blockIdx.x * 4096 + (size_t)threadIdx.x * 4;
#pragma unroll
  for (int j = 0; j < 4; j++) {
    size_t i = base + (size_t)j * 1024;
    const float* src;
    size_t soff = i;
    if (y < 3) {
      src = (y == 0) ? q : (y == 1) ? k : v;
    } else {
      int w = (int)(i >> 20);  // NW_ = 2^20 elems per weight; uniform per block
      src = (w == 0) ? w0 : (w == 1) ? w1 : (w == 2) ? w2 : w3;
      soff = i & (NW_ - 1);
    }
    float4 vv = *(const float4*)(src + soff);
    union { bf16 h[4]; uint2 u; } pk;
    pk.h[0] = __float2bfloat16(vv.x);
    pk.h[1] = __float2bfloat16(vv.y);
    pk.h[2] = __float2bfloat16(vv.z);
    pk.h[3] = __float2bfloat16(vv.w);
    *(uint2*)(dst + (size_t)y * NA_ + i) = pk.u;
  }
}

// Fused Q/K/V projection, pure-bf16 m97 pattern (BK=32). grid (32,8,3), XCD swz.
// z==2 (V) epilogue: LDS transpose -> coalesced 16B stores into vt [B,H,HD,L].
#define TS_ 136  // transpose-tile elem stride (272B rows, 16B aligned)
__global__ __launch_bounds__(256) void gemm_qkv(const bf16* __restrict__ Qb,
                                                const bf16* __restrict__ Kb,
                                                const bf16* __restrict__ Vb,
                                                const bf16* __restrict__ Wb,
                                                bf16* __restrict__ qp,
                                                bf16* __restrict__ kp,
                                                bf16* __restrict__ vtp) {
  __shared__ __align__(16) bf16 smem[128 * TS_];  // As(4K) + Bs(4K) | T(17K elems)
  bf16* As = smem;
  bf16* Bs = smem + 128 * 32;
  const int tid = threadIdx.x;
  const int wv = tid >> 6, lane = tid & 63;
  const int quad = lane >> 4, l16 = lane & 15;
  const int wm = wv & 1, wn = wv >> 1;
  // XCD-chunked swizzle: 768 blocks = 8 XCDs x 96.
  const int id = blockIdx.x + 32 * blockIdx.y + 256 * blockIdx.z;
  const int swz = (id & 7) * 96 + (id >> 3);
  const int m0 = (swz & 31) * 128, n0 = ((swz >> 5) & 7) * 128;
  const int z = swz >> 8;
  const bf16* X = (z == 0) ? Qb : (z == 1) ? Kb : Vb;
  const bf16* W = Wb + (size_t)z * NW_;

  f32x4 acc[4][4];
#pragma unroll
  for (int i = 0; i < 4; i++)
#pragma unroll
    for (int j = 0; j < 4; j++) acc[i][j] = (f32x4){0.f, 0.f, 0.f, 0.f};

  for (int k0 = 0; k0 < D_; k0 += 32) {
#pragma unroll
    for (int it = 0; it < 2; it++) {
      int c = (wv * 2 + it) * 64 + lane;
      int row = c >> 2, cc = c & 3;
      async_load16(X + (size_t)(m0 + row) * D_ + k0 + cc * 8, (char*)As + c * 16);
      async_load16(W + (size_t)(n0 + row) * D_ + k0 + cc * 8, (char*)Bs + c * 16);
    }
    __syncthreads();
    bf16x8 af[4], bfr[4];
#pragma unroll
    for (int mi = 0; mi < 4; mi++)
      af[mi] = *(const bf16x8*)&As[(wm * 64 + mi * 16 + l16) * 32 + quad * 8];
#pragma unroll
    for (int ni = 0; ni < 4; ni++)
      bfr[ni] = *(const bf16x8*)&Bs[(wn * 64 + ni * 16 + l16) * 32 + quad * 8];
#pragma unroll
    for (int mi = 0; mi < 4; mi++)
#pragma unroll
      for (int ni = 0; ni < 4; ni++)
        acc[mi][ni] = __builtin_amdgcn_mfma_f32_16x16x32_bf16(af[mi], bfr[ni],
                                                              acc[mi][ni], 0, 0, 0);
    __syncthreads();
  }

  if (z == 2) {
    // Transpose epilogue: T[n_loc][m_loc], 4 m-consecutive accs -> ds_write_b64.
    bf16* T = smem;
#pragma unroll
    for (int mi = 0; mi < 4; mi++) {
#pragma unroll
      for (int ni = 0; ni < 4; ni++) {
        int n_loc = wn * 64 + ni * 16 + l16;
        int m_loc = wm * 64 + mi * 16 + quad * 4;
        union { bf16 hx[4]; uint2 d; } pk;
#pragma unroll
        for (int r = 0; r < 4; r++) pk.hx[r] = __float2bfloat16(acc[mi][ni][r]);
        *(uint2*)&T[n_loc * TS_ + m_loc] = pk.d;
      }
    }
    __syncthreads();
    // 8 passes: 16 threads per n-row read b128 (m-contig) -> 256B coalesced store.
#pragma unroll
    for (int p = 0; p < 8; p++) {
      int n_loc = p * 16 + (tid >> 4);
      int m_loc = (tid & 15) * 8;
      bf16x8 vv = *(const bf16x8*)&T[n_loc * TS_ + m_loc];
      int n = n0 + n_loc;
      int m = m0 + m_loc;
      int bb = m >> 11, l = m & (L_ - 1);
      int hh = n >> 6, hd = n & 63;
      *(bf16x8*)&vtp[((size_t)((bb * H_ + hh) * HD_ + hd)) * L_ + l] = vv;
    }
  } else {
    // qp pre-scaled by 0.125 * log2(e) so attn softmax is a bare v_exp_f32.
    const float sc = (z == 0) ? 0.18033688f : 1.0f;
    bf16* dst = (z == 0) ? qp : kp;
#pragma unroll
    for (int mi = 0; mi < 4; mi++) {
#pragma unroll
      for (int ni = 0; ni < 4; ni++) {
        int n = n0 + wn * 64 + ni * 16 + l16;
#pragma unroll
        for (int r = 0; r < 4; r++) {
          int m = m0 + wm * 64 + mi * 16 + quad * 4 + r;
          dst[(size_t)m * D_ + n] = __float2bfloat16(acc[mi][ni][r] * sc);
        }
      }
    }
  }
}

// Unpaired causal flash attention. grid (H, 32, B) = 1024 blocks,
// band = 31 - blockIdx.y (longest bands dispatch first). 3 blocks/CU.
// S^T = mfma(K,Q): lane(l16) owns q-row, 4 consecutive keys per (ss,quad).
// Softmax: raw 2^x (log2e pre-folded into qp), rcp normalize.
__global__ __launch_bounds__(256) void attn_kernel(const bf16* __restrict__ qp,
                                                   const bf16* __restrict__ kp,
                                                   const bf16* __restrict__ vt,
                                                   bf16* __restrict__ attn) {
  __shared__ __align__(16) bf16 Kt[2][64 * 64];  // swizzled [key][hd]
  __shared__ __align__(16) bf16 Vt[2][64 * 64];  // swizzled [hd][key]
  __shared__ __align__(16) bf16 P[4][16 * 72];   // per-wave [q][key]
  const int tid = threadIdx.x;
  const int wv = tid >> 6, lane = tid & 63;
  const int quad = lane >> 4, l16 = lane & 15;
  const int h = blockIdx.x, band = 31 - (int)blockIdx.y, b = blockIdx.z;

  const int rq = band * 64 + wv * 16 + l16;  // this lane's q-row (S^T col)
  bf16x8 qa[2];
#pragma unroll
  for (int kk = 0; kk < 2; kk++)
    qa[kk] = *(const bf16x8*)&qp[((size_t)(b * L_ + rq)) * D_ + h * HD_ +
                                 kk * 32 + quad * 8];

  f32x4 O[4];
#pragma unroll
  for (int t = 0; t < 4; t++) O[t] = (f32x4){0.f, 0.f, 0.f, 0.f};
  float l = 0.f;  // per-lane row sum for q = rq

  const int csw = quad ^ (l16 & 7);  // swizzled base chunk for frag reads

  auto stage = [&](int j, int buf) {
    const int j0 = j * 64;
#pragma unroll
    for (int it = 0; it < 2; it++) {
      int slot = (wv * 2 + it) * 64 + lane;
      int row = slot >> 3, c = (slot & 7) ^ (row & 7);
      async_load16(kp + ((size_t)(b * L_ + j0 + row)) * D_ + h * HD_ + c * 8,
                   (char*)Kt[buf] + slot * 16);
      async_load16(vt + ((size_t)((b * H_ + h) * HD_ + row)) * L_ + j0 + c * 8,
                   (char*)Vt[buf] + slot * 16);
    }
  };

  stage(0, 0);
  for (int j = 0; j <= band; j++) {
    const int buf = j & 1;
    const int j0 = j * 64;
    __syncthreads();
    if (j < band) stage(j + 1, buf ^ 1);

    // S^T = K Q^T (0.125*log2e pre-folded): s[ss][r] = S[key][q=l16-row]
    f32x4 s[4];
    __builtin_amdgcn_s_setprio(1);
#pragma unroll
    for (int ss = 0; ss < 4; ss++) {
      int krow = ss * 16 + l16;
      bf16x8 kb0 = *(const bf16x8*)&Kt[buf][krow * 64 + csw * 8];
      bf16x8 kb1 = *(const bf16x8*)&Kt[buf][krow * 64 + (csw ^ 4) * 8];
      f32x4 t = (f32x4){0.f, 0.f, 0.f, 0.f};
      t = __builtin_amdgcn_mfma_f32_16x16x32_bf16(kb0, qa[0], t, 0, 0, 0);
      t = __builtin_amdgcn_mfma_f32_16x16x32_bf16(kb1, qa[1], t, 0, 0, 0);
      s[ss] = t;
    }
    __builtin_amdgcn_s_setprio(0);

    if (j == band) {  // diagonal tile: causal mask
#pragma unroll
      for (int ss = 0; ss < 4; ss++)
#pragma unroll
        for (int r = 0; r < 4; r++) {
          int key = j0 + ss * 16 + quad * 4 + r;
          if (key > rq) s[ss][r] = -1e30f;
        }
    }

    // 2^s + pack 4 consecutive keys -> one ds_write_b64 per ss (wave-private).
#pragma unroll
    for (int ss = 0; ss < 4; ss++) {
      float p0 = fast_exp2(s[ss][0]), p1 = fast_exp2(s[ss][1]);
      float p2 = fast_exp2(s[ss][2]), p3 = fast_exp2(s[ss][3]);
      l += (p0 + p1) + (p2 + p3);
      union { bf16 hx[4]; uint2 d; } pk;
      pk.hx[0] = __float2bfloat16(p0);
      pk.hx[1] = __float2bfloat16(p1);
      pk.hx[2] = __float2bfloat16(p2);
      pk.hx[3] = __float2bfloat16(p3);
      *(uint2*)&P[wv][l16 * 72 + ss * 16 + quad * 4] = pk.d;
    }

    // P region is per-wave: order writes->reads without draining vmcnt.
    asm volatile("s_waitcnt lgkmcnt(0)" ::: "memory");

    // O += P V
    __builtin_amdgcn_s_setprio(1);
#pragma unroll
    for (int kk = 0; kk < 2; kk++) {
      bf16x8 pa = *(const bf16x8*)&P[wv][l16 * 72 + kk * 32 + quad * 8];
#pragma unroll
      for (int t = 0; t < 4; t++) {
        bf16x8 vb = *(const bf16x8*)&Vt[buf][(t * 16 + l16) * 64 + (csw ^ (kk * 4)) * 8];
        O[t] = __builtin_amdgcn_mfma_f32_16x16x32_bf16(pa, vb, O[t], 0, 0, 0);
      }
    }
    __builtin_amdgcn_s_setprio(0);
  }

  // Row sums: quad-reduce (2 shuffles), redistribute to fragment rows,
  // then approximate-reciprocal normalize (bf16 output: 1ulp rcp is plenty).
  l += __shfl_xor(l, 16, 64);
  l += __shfl_xor(l, 32, 64);
  float rl[4];
#pragma unroll
  for (int r = 0; r < 4; r++)
    rl[r] = __builtin_amdgcn_rcpf(__shfl(l, quad * 4 + r, 64));

#pragma unroll
  for (int t = 0; t < 4; t++) {
#pragma unroll
    for (int r = 0; r < 4; r++) {
      int row = band * 64 + wv * 16 + quad * 4 + r;
      attn[((size_t)(b * L_ + row)) * D_ + h * HD_ + t * 16 + l16] =
          __float2bfloat16(O[t][r] * rl[r]);
    }
  }
}

// out = at @ wo^T + bo, f32 store. 128x128 m97 tiles (BK=32) -> grid (32, 8)
// = 256 blocks = exactly 1/CU (tail-free), XCD-chunked swizzle (256 = 8*32).
__global__ __launch_bounds__(256) void gemm_out(const bf16* __restrict__ X,
                                                const bf16* __restrict__ W,
                                                const float* __restrict__ bias,
                                                float* __restrict__ out) {
  __shared__ __align__(16) bf16 As[128 * 32];
  __shared__ __align__(16) bf16 Bs[128 * 32];
  const int tid = threadIdx.x;
  const int wv = tid >> 6, lane = tid & 63;
  const int quad = lane >> 4, l16 = lane & 15;
  const int wm = wv & 1, wn = wv >> 1;
  const int id = blockIdx.x + 32 * blockIdx.y;
  const int swz = (id & 7) * 32 + (id >> 3);
  const int m0 = (swz & 31) * 128, n0 = (swz >> 5) * 128;

  f32x4 acc[4][4];
#pragma unroll
  for (int i = 0; i < 4; i++)
#pragma unroll
    for (int j = 0; j < 4; j++) acc[i][j] = (f32x4){0.f, 0.f, 0.f, 0.f};

  for (int k0 = 0; k0 < D_; k0 += 32) {
#pragma unroll
    for (int it = 0; it < 2; it++) {
      int c = (wv * 2 + it) * 64 + lane;
      int row = c >> 2, cc = c & 3;
      async_load16(X + (size_t)(m0 + row) * D_ + k0 + cc * 8, (char*)As + c * 16);
      async_load16(W + (size_t)(n0 + row) * D_ + k0 + cc * 8, (char*)Bs + c * 16);
    }
    __syncthreads();
    bf16x8 af[4], bfr[4];
#pragma unroll
    for (int mi = 0; mi < 4; mi++)
      af[mi] = *(const bf16x8*)&As[(wm * 64 + mi * 16 + l16) * 32 + quad * 8];
#pragma unroll
    for (int ni = 0; ni < 4; ni++)
      bfr[ni] = *(const bf16x8*)&Bs[(wn * 64 + ni * 16 + l16) * 32 + quad * 8];
#pragma unroll
    for (int mi = 0; mi < 4; mi++)
#pragma unroll
      for (int ni = 0; ni < 4; ni++)
        acc[mi][ni] = __builtin_amdgcn_mfma_f32_16x16x32_bf16(af[mi], bfr[ni],
                                                              acc[mi][ni], 0, 0, 0);
    __syncthreads();
  }

#pragma unroll
  for (int mi = 0; mi < 4; mi++) {
#pragma unroll
    for (int ni = 0; ni < 4; ni++) {
      int n = n0 + wn * 64 + ni * 16 + l16;
      float bval = bias[n];
#pragma unroll
      for (int r = 0; r < 4; r++) {
        int m = m0 + wm * 64 + mi * 16 + quad * 4 + r;
        out[(size_t)m * D_ + n] = acc[mi][ni][r] + bval;
      }
    }
  }
}

extern "C" void kernel_launch(void* const* d_in, const int* in_sizes, int n_in,
                              void* d_out, int out_size, void* d_ws, size_t ws_size,
                              hipStream_t stream) {
  const float* Q  = (const float*)d_in[0];
  const float* K  = (const float*)d_in[1];
  const float* V  = (const float*)d_in[2];
  // d_in[3]: causal mask (int32) -- deterministic tril, not read
  const float* wq = (const float*)d_in[4];
  const float* wk = (const float*)d_in[5];
  const float* wvp = (const float*)d_in[6];
  const float* wo = (const float*)d_in[7];
  const float* bo = (const float*)d_in[8];
  float* out = (float*)d_out;

  bf16* base = (bf16*)d_ws;           // packed: Qb,Kb,Vb, W[4], qp,kp,vt,at
  bf16* Qb = base;
  bf16* Kb = Qb + NA_;
  bf16* Vb = Kb + NA_;
  bf16* Wb = Vb + NA_;                // 4 weights
  bf16* qp = Wb + 4 * NW_;
  bf16* kp = qp + NA_;
  bf16* vt = kp + NA_;
  bf16* at = vt + NA_;                // total 64 MB

  xcvt_kernel<<<dim3(NA_ / 4096, 4), 256, 0, stream>>>(Q, K, V, wq, wk, wvp, wo, base);
  gemm_qkv<<<dim3(32, 8, 3), 256, 0, stream>>>(Qb, Kb, Vb, Wb, qp, kp, vt);
  attn_kernel<<<dim3(H_, L_ / 64, B_), 256, 0, stream>>>(qp, kp, vt, at);
  gemm_out<<<dim3(32, 8), 256, 0, stream>>>(at, Wb + 3 * NW_, bo, out);
}